// Round 5
// baseline (268.575 us; speedup 1.0000x reference)
//
#include <hip/hip_runtime.h>
#include <hip/hip_bf16.h>
#include <math.h>

#define BS 128
#define NN 320
#define H1 8
#define F1 18
#define D1 144
#define H2C 4
#define F2 46
#define FC0 104
#define FC1 45
#define FC2 84
#define LRA 0.2f
#define DEGCAP 96

typedef __attribute__((ext_vector_type(8))) short bf16x8;
typedef __attribute__((ext_vector_type(4))) float f32x4;

__device__ __forceinline__ float wave_max64(float v) {
    #pragma unroll
    for (int off = 32; off > 0; off >>= 1)
        v = fmaxf(v, __shfl_xor(v, off, 64));
    return v;
}
__device__ __forceinline__ float wave_sum64(float v) {
    #pragma unroll
    for (int off = 32; off > 0; off >>= 1)
        v += __shfl_xor(v, off, 64);
    return v;
}
__device__ __forceinline__ short bfb(float x) {
    __hip_bfloat16 b = __float2bfloat16(x);
    return *(short*)&b;
}

// ---- K0: CSR build (u16, fwd + transposed) + l1 consts + Bb pack -----------
__global__ void k_csr(const float* __restrict__ adj,
                      unsigned short* __restrict__ cols16,
                      unsigned short* __restrict__ colsT16,
                      int* __restrict__ len, const float* __restrict__ W1,
                      const float* __restrict__ a1, float* __restrict__ c1s,
                      float* __restrict__ c1d, const float* __restrict__ W2,
                      __hip_bfloat16* __restrict__ Bb) {
    int row = blockIdx.x;
    int lane = threadIdx.x;  // 64 threads
    if (row < NN) {
        int base = 0;
        for (int c0 = 0; c0 < NN; c0 += 64) {
            int j = c0 + lane;
            bool p = (j < NN) && (adj[row * NN + j] > 0.f);
            unsigned long long m = __ballot(p);
            if (p) {
                int pos = base + __popcll(m & ((1ull << lane) - 1ull));
                if (pos < DEGCAP) {
                    cols16[row * DEGCAP + pos] = (unsigned short)j;
                    colsT16[pos * NN + row] = (unsigned short)j;
                }
            }
            base += __popcll(m);
        }
        if (base > DEGCAP) base = DEGCAP;
        for (int q = base + lane; q < DEGCAP; q += 64) {
            cols16[row * DEGCAP + q] = 0;
            colsT16[q * NN + row] = 0;
        }
        if (lane == 0) len[row] = base;
    } else if (row == NN) {
        int h = lane;
        if (h < H1) {
            float s = 0.f, d = 0.f;
            for (int f = 0; f < F1; ++f) {
                float w = W1[h * F1 + f];
                s += w * a1[h * 2 * F1 + f];
                d += w * a1[h * 2 * F1 + F1 + f];
            }
            c1s[h] = s;
            c1d[h] = d;
        }
    } else {
        // Bb[k8][n][e]: n = h*48+f; zero pad cols f>=46 and k>=144
        int idx = (row - NN - 1) * 64 + lane;   // 0..30719
        int e = idx & 7;
        int t = idx >> 3;
        int n = t % 192, k8 = t / 192;
        int k = k8 * 8 + e, hh = n / 48, f = n - hh * 48;
        float v = (k < 144 && f < 46) ? W2[(hh * 144 + k) * 46 + f] : 0.f;
        Bb[idx] = __float2bfloat16(v);
    }
}

// ---- K1: layer-1 GAT, lanes=rows ------------------------------------------
__global__ __launch_bounds__(320) void k_gat1(
    const float* __restrict__ xn, const unsigned short* __restrict__ colsT16,
    const int* __restrict__ len, const float* __restrict__ W1,
    const float* __restrict__ c1s, const float* __restrict__ c1d,
    const float* __restrict__ p1w, __hip_bfloat16* __restrict__ out1b,
    float* __restrict__ part1) {
    int b = blockIdx.x >> 1, hg = blockIdx.x & 1;
    __shared__ float xb[NN];
    __shared__ float stab[4][NN];
    __shared__ float w1h[4][F1], pwl[4][F1];
    __shared__ float redmax[5], redmin[5];
    int tid = threadIdx.x;          // == row
    int wv = tid >> 6, lane = tid & 63;
    float xi = xn[b * NN + tid];
    xb[tid] = xi;
    if (tid < 72) {
        int hh = tid / F1, f = tid - hh * F1;
        w1h[hh][f] = W1[(hg * 4 + hh) * F1 + f];
        pwl[hh][f] = p1w[(hg * 4 + hh) * F1 + f];
    }
    int Li = len[tid];
    float mx = wave_max64(xi);
    float mn = -wave_max64(-xi);
    int Lmax = (int)wave_max64((float)Li);
    if (lane == 0) { redmax[wv] = mx; redmin[wv] = mn; }
    __syncthreads();
    float MX = redmax[0], MN = redmin[0];
    #pragma unroll
    for (int q = 1; q < 5; ++q) {
        MX = fmaxf(MX, redmax[q]);
        MN = fminf(MN, redmin[q]);
    }
    float u[4], m[4], num[4], den[4], cd[4];
    #pragma unroll
    for (int hh = 0; hh < 4; ++hh) {
        float cs = c1s[hg * 4 + hh];
        cd[hh] = c1d[hg * 4 + hh];
        u[hh] = xi * cs;
        float mt = u[hh] + (cd[hh] > 0.f ? cd[hh] * MX : cd[hh] * MN);
        m[hh] = fmaxf(mt, LRA * mt);
        num[hh] = 0.f; den[hh] = 0.f;
    }
    const unsigned short* ct = colsT16 + tid;
    int colv = ct[0];
    for (int j = 0; j < Lmax; ++j) {
        int coln = (j + 1 < Lmax) ? ct[(j + 1) * NN] : 0;
        float xj = xb[colv];
        bool act = j < Li;
        #pragma unroll
        for (int hh = 0; hh < 4; ++hh) {
            float t = fmaf(xj, cd[hh], u[hh]);
            t = fmaxf(t, LRA * t);
            float w = __expf(t - m[hh]);
            w = act ? w : 0.f;
            num[hh] = fmaf(w, xj, num[hh]);
            den[hh] += w;
        }
        colv = coln;
    }
    #pragma unroll
    for (int hh = 0; hh < 4; ++hh) stab[hh][tid] = num[hh] / den[hh];
    __syncthreads();
    if (hg == 0) {
        for (int idx = tid; idx < NN * 72; idx += 320) {
            int row = idx / 72, c = idx - row * 72;
            int hh = c / F1, f = c - hh * F1;
            float v = stab[hh][row] * w1h[hh][f];
            v = v > 0.f ? v : expm1f(v);
            out1b[(size_t)(b * NN + row) * 160 + c] = __float2bfloat16(v);
        }
    } else {
        for (int idx = tid; idx < NN * 88; idx += 320) {
            int row = idx / 88, c = idx - row * 88;
            float v = 0.f;
            if (c < 72) {
                int hh = c / F1, f = c - hh * F1;
                v = stab[hh][row] * w1h[hh][f];
                v = v > 0.f ? v : expm1f(v);
            }
            out1b[(size_t)(b * NN + row) * 160 + 72 + c] = __float2bfloat16(v);
        }
    }
    float part = 0.f;
    #pragma unroll
    for (int hh = 0; hh < 4; ++hh) {
        float s = stab[hh][tid];
        #pragma unroll
        for (int f = 0; f < F1; ++f) {
            float v = s * w1h[hh][f];
            v = v > 0.f ? v : expm1f(v);
            part = fmaf(v, pwl[hh][f], part);
        }
    }
    part1[(size_t)(b * 2 + hg) * NN + tid] = part;
}

// ---- K3: h2T = (out1 @ W2)^T via bf16 MFMA + es/ed partial epilogue --------
__global__ __launch_bounds__(256) void k_gemm2(
    const __hip_bfloat16* __restrict__ A,    // [40960][160] bf16
    const __hip_bfloat16* __restrict__ Bb,   // [20][192][8] bf16
    const float* __restrict__ a2,
    __hip_bfloat16* __restrict__ h2T,        // [512][48][320]
    float* __restrict__ esp, float* __restrict__ edp) {  // [2][512][320]
    __shared__ __align__(16) __hip_bfloat16 As[64 * 168];
    __shared__ __align__(16) __hip_bfloat16 Bs[20 * 96 * 8];
    __shared__ float a2e[4][48], a2d[4][48];
    int tid = threadIdx.x;
    int mblk = blockIdx.x >> 1, hblk = blockIdx.x & 1;
    int r0 = mblk * 64;
    const uint4* Ag = (const uint4*)(A + (size_t)r0 * 160);
    for (int q = tid; q < 1280; q += 256) {
        int row = q / 20, k8 = q % 20;
        *(uint4*)(As + row * 168 + k8 * 8) = Ag[q];
    }
    const uint4* Bg = (const uint4*)Bb;
    for (int q = tid; q < 1920; q += 256) {
        int k8 = q / 96, nl = q % 96;
        *(uint4*)(Bs + (k8 * 96 + nl) * 8) = Bg[k8 * 192 + hblk * 96 + nl];
    }
    if (tid < 192) {
        int hh = tid / 48, f = tid - hh * 48;
        a2e[hh][f] = f < 46 ? a2[hh * 92 + f] : 0.f;
        a2d[hh][f] = f < 46 ? a2[hh * 92 + 46 + f] : 0.f;
    }
    __syncthreads();
    int wv = tid >> 6, l = tid & 63;
    int lr = l & 15, lq = l >> 4;
    bf16x8 af[5];
    const __hip_bfloat16* arow = As + (wv * 16 + lr) * 168 + lq * 8;
    #pragma unroll
    for (int kc = 0; kc < 5; ++kc)
        af[kc] = *(const bf16x8*)(arow + kc * 32);
    f32x4 acc[6];
    #pragma unroll
    for (int t = 0; t < 6; ++t) acc[t] = (f32x4){0.f, 0.f, 0.f, 0.f};
    #pragma unroll
    for (int t = 0; t < 6; ++t) {
        const __hip_bfloat16* bcol = Bs + (t * 16 + lr) * 8;
        #pragma unroll
        for (int kc = 0; kc < 5; ++kc) {
            bf16x8 bf = *(const bf16x8*)(bcol + (kc * 4 + lq) * 768);
            acc[t] = __builtin_amdgcn_mfma_f32_16x16x32_bf16(af[kc], bf, acc[t], 0, 0, 0);
        }
    }
    int b = r0 / NN;
    int nbase = (r0 % NN) + wv * 16 + lq * 4;
    #pragma unroll
    for (int t = 0; t < 6; ++t) {
        int hh = 2 * hblk + (t >= 3);
        int f = (t % 3) * 16 + lr;
        short4 s4;
        s4.x = bfb(acc[t][0]); s4.y = bfb(acc[t][1]);
        s4.z = bfb(acc[t][2]); s4.w = bfb(acc[t][3]);
        *(short4*)(h2T + ((size_t)(b * 4 + hh) * 48 + f) * NN + nbase) = s4;
    }
    float esa[2][4], eda[2][4];
    #pragma unroll
    for (int hs = 0; hs < 2; ++hs)
        #pragma unroll
        for (int j = 0; j < 4; ++j) { esa[hs][j] = 0.f; eda[hs][j] = 0.f; }
    #pragma unroll
    for (int t = 0; t < 6; ++t) {
        int hs = (t >= 3);
        int hh = 2 * hblk + hs;
        int f = (t % 3) * 16 + lr;
        float ae = a2e[hh][f], ad = a2d[hh][f];
        #pragma unroll
        for (int j = 0; j < 4; ++j) {
            esa[hs][j] = fmaf(acc[t][j], ae, esa[hs][j]);
            eda[hs][j] = fmaf(acc[t][j], ad, eda[hs][j]);
        }
    }
    #pragma unroll
    for (int hs = 0; hs < 2; ++hs)
        #pragma unroll
        for (int j = 0; j < 4; ++j) {
            #pragma unroll
            for (int off = 1; off < 16; off <<= 1) {
                esa[hs][j] += __shfl_xor(esa[hs][j], off, 64);
                eda[hs][j] += __shfl_xor(eda[hs][j], off, 64);
            }
        }
    if (lr == 0) {
        #pragma unroll
        for (int hs = 0; hs < 2; ++hs) {
            int bh = b * 4 + 2 * hblk + hs;
            #pragma unroll
            for (int j = 0; j < 4; ++j) {
                esp[(size_t)hblk * 512 * NN + (size_t)bh * NN + nbase + j] = esa[hs][j];
                edp[(size_t)hblk * 512 * NN + (size_t)bh * NN + nbase + j] = eda[hs][j];
            }
        }
    }
}

// ---- K4: layer-2 GAT: sparse P-fill + dense MFMA aggregation ---------------
__global__ __launch_bounds__(256) void k_gat2(
    const __hip_bfloat16* __restrict__ h2T,  // [512][48][320]
    const float* __restrict__ esp, const float* __restrict__ edp,
    const unsigned short* __restrict__ cols16, const int* __restrict__ len,
    const float* __restrict__ p2w, float* __restrict__ part2) {
    int bh = blockIdx.x / 5, tile = blockIdx.x - 5 * (blockIdx.x / 5);
    int h = bh & 3;
    int r0 = tile * 64;
    __shared__ __align__(16) __hip_bfloat16 P[64][328];  // 41984 B
    __shared__ float esl[64], denl[64], edl[NN];
    __shared__ float pwl[48];
    __shared__ int lenl[64];
    __shared__ float Mred[4];
    int tid = threadIdx.x, wv = tid >> 6, lane = tid & 63;
    float edmax = -1e30f;
    for (int j = tid; j < NN; j += 256) {
        float ed = edp[(size_t)bh * NN + j] +
                   edp[(size_t)512 * NN + (size_t)bh * NN + j];
        edl[j] = ed;
        edmax = fmaxf(edmax, ed);
    }
    if (tid < 64) {
        esl[tid] = esp[(size_t)bh * NN + r0 + tid] +
                   esp[(size_t)512 * NN + (size_t)bh * NN + r0 + tid];
        lenl[tid] = len[r0 + tid];
    }
    if (tid < 48) pwl[tid] = tid < 46 ? p2w[h * F2 + tid] : 0.f;
    float wm = wave_max64(edmax);
    if (lane == 0) Mred[wv] = wm;
    for (int q = tid; q < 64 * 328 / 8; q += 256)
        ((uint4*)&P[0][0])[q] = (uint4){0u, 0u, 0u, 0u};
    __syncthreads();
    float M = fmaxf(fmaxf(Mred[0], Mred[1]), fmaxf(Mred[2], Mred[3]));
    // phase 1: fill P rows wv*16..+16 (lanes = neighbors)
    for (int r = 0; r < 16; ++r) {
        int row = wv * 16 + r;
        int i = r0 + row;
        int L = lenl[row];
        float es = esl[row];
        float t0 = es + M;
        float m = fmaxf(t0, LRA * t0);
        float dacc = 0.f;
        for (int c0 = 0; c0 < L; c0 += 64) {
            int idx = c0 + lane;
            bool act = idx < L;
            int col = act ? cols16[i * DEGCAP + idx] : 0;
            float t = es + edl[col];
            t = fmaxf(t, LRA * t);
            float w = __expf(t - m);
            w = act ? w : 0.f;
            dacc += w;
            if (act) P[row][col] = __float2bfloat16(w);
        }
        float den = wave_sum64(dacc);
        if (lane == 0) denl[row] = den;
    }
    __syncthreads();
    // phase 2: C[64x48] = P @ H^T, m-tile = wv
    int lr = lane & 15, lq = lane >> 4;
    f32x4 acc[3];
    #pragma unroll
    for (int t = 0; t < 3; ++t) acc[t] = (f32x4){0.f, 0.f, 0.f, 0.f};
    const __hip_bfloat16* Bbase = h2T + (size_t)bh * 48 * NN;
    const __hip_bfloat16* Arow = &P[wv * 16 + lr][lq * 8];
    #pragma unroll 2
    for (int k = 0; k < 10; ++k) {
        bf16x8 a = *(const bf16x8*)(Arow + k * 32);
        #pragma unroll
        for (int t = 0; t < 3; ++t) {
            bf16x8 bf = *(const bf16x8*)(Bbase + (t * 16 + lr) * NN + k * 32 + lq * 8);
            acc[t] = __builtin_amdgcn_mfma_f32_16x16x32_bf16(a, bf, acc[t], 0, 0, 0);
        }
    }
    float inv[4], part[4];
    #pragma unroll
    for (int j = 0; j < 4; ++j) {
        inv[j] = 1.f / denl[wv * 16 + lq * 4 + j];
        part[j] = 0.f;
    }
    #pragma unroll
    for (int t = 0; t < 3; ++t) {
        float pw = pwl[t * 16 + lr];
        #pragma unroll
        for (int j = 0; j < 4; ++j) {
            float v = acc[t][j] * inv[j];
            v = v > 0.f ? v : expm1f(v);
            part[j] = fmaf(v, pw, part[j]);
        }
    }
    #pragma unroll
    for (int j = 0; j < 4; ++j) {
        #pragma unroll
        for (int off = 1; off < 16; off <<= 1)
            part[j] += __shfl_xor(part[j], off, 64);
    }
    if (lr == 0) {
        #pragma unroll
        for (int j = 0; j < 4; ++j)
            part2[(size_t)bh * NN + r0 + wv * 16 + lq * 4 + j] = part[j];
    }
}

// ---- K5: x_concat assembly + FC head ---------------------------------------
__global__ __launch_bounds__(128) void k_head(
    const float* __restrict__ xn, const float* __restrict__ part1,
    const float* __restrict__ part2, const float* __restrict__ p1b,
    const float* __restrict__ p2b, const float* __restrict__ e1w,
    const float* __restrict__ e1b, const float* __restrict__ e2w,
    const float* __restrict__ e2b, const float* __restrict__ e3w,
    const float* __restrict__ e3b, const float* __restrict__ cw,
    const float* __restrict__ cb, float* __restrict__ dout) {
    int b = blockIdx.x;
    int tid = threadIdx.x;
    __shared__ float xc[960];
    __shared__ float h1[FC0];
    __shared__ float hh[FC1];
    __shared__ float ft[FC2];
    for (int t = tid; t < NN; t += 128) {
        float x0 = xn[b * NN + t];
        xc[t] = x0;
        dout[b * 960 + t] = x0;
        float s1 = p1b[0] + part1[(size_t)(b * 2) * NN + t] +
                   part1[(size_t)(b * 2 + 1) * NN + t];
        xc[320 + t] = s1;
        dout[b * 960 + 320 + t] = s1;
        float s2 = p2b[0];
        #pragma unroll
        for (int h = 0; h < 4; ++h) s2 += part2[(size_t)(b * 4 + h) * NN + t];
        xc[640 + t] = s2;
        dout[b * 960 + 640 + t] = s2;
    }
    __syncthreads();
    if (tid < FC0) {
        float a = e1b[tid];
        for (int k = 0; k < 960; ++k) a += xc[k] * e1w[k * FC0 + tid];
        h1[tid] = a > 0.f ? a : expm1f(a);
    }
    __syncthreads();
    if (tid < FC1) {
        float a = e2b[tid];
        for (int k = 0; k < FC0; ++k) a += h1[k] * e2w[k * FC1 + tid];
        hh[tid] = a > 0.f ? a : expm1f(a);
    }
    __syncthreads();
    if (tid < FC2) {
        float a = e3b[tid];
        for (int k = 0; k < FC1; ++k) a += hh[k] * e3w[k * FC2 + tid];
        a = a > 0.f ? a : expm1f(a);
        ft[tid] = a;
        dout[BS * 960 + b * FC2 + tid] = a;
    }
    __syncthreads();
    if (tid < 64) {
        float v = 0.f;
        for (int t = tid; t < FC2; t += 64) v += ft[t] * cw[t];
        v = wave_sum64(v);
        if (tid == 0) dout[BS * 960 + BS * FC2 + b] = v + cb[0];
    }
}

extern "C" void kernel_launch(void* const* d_in, const int* in_sizes, int n_in,
                              void* d_out, int out_size, void* d_ws,
                              size_t ws_size, hipStream_t stream) {
    const float* xn  = (const float*)d_in[0];
    const float* adj = (const float*)d_in[1];
    const float* W1  = (const float*)d_in[2];
    const float* a1  = (const float*)d_in[3];
    const float* W2  = (const float*)d_in[4];
    const float* a2  = (const float*)d_in[5];
    const float* p1w = (const float*)d_in[6];
    const float* p1b = (const float*)d_in[7];
    const float* p2w = (const float*)d_in[8];
    const float* p2b = (const float*)d_in[9];
    const float* e1w = (const float*)d_in[10];
    const float* e1b = (const float*)d_in[11];
    const float* e2w = (const float*)d_in[12];
    const float* e2b = (const float*)d_in[13];
    const float* e3w = (const float*)d_in[14];
    const float* e3b = (const float*)d_in[15];
    const float* cw  = (const float*)d_in[16];
    const float* cb  = (const float*)d_in[17];

    char* ws = (char*)d_ws;
    int*   csr_len  = (int*)ws;                                // [0, 1280)
    float* c1s      = (float*)(ws + 1280);
    float* c1d      = (float*)(ws + 1312);                     // pad -> 1536
    unsigned short* cols16  = (unsigned short*)(ws + 1536);    // 61440 -> 62976
    unsigned short* colsT16 = (unsigned short*)(ws + 62976);   // 61440 -> 124416
    __hip_bfloat16* Bb    = (__hip_bfloat16*)(ws + 124416);    // 61440 -> 185856
    __hip_bfloat16* out1b = (__hip_bfloat16*)(ws + 185856);    // 13107200 -> 13293056
    __hip_bfloat16* h2T   = (__hip_bfloat16*)(ws + 13293056);  // 15728640 -> 29021696
    float* esp      = (float*)(ws + 29021696);                 // 1310720 -> 30332416
    float* edp      = (float*)(ws + 30332416);                 // 1310720 -> 31643136
    float* part1    = (float*)(ws + 31643136);                 // 327680 -> 31970816
    float* part2    = (float*)(ws + 31970816);                 // 655360 -> 32626176
    float* dout     = (float*)d_out;

    k_csr<<<NN + 1 + 480, 64, 0, stream>>>(adj, cols16, colsT16, csr_len,
                                           W1, a1, c1s, c1d, W2, Bb);
    k_gat1<<<BS * 2, 320, 0, stream>>>(xn, colsT16, csr_len, W1, c1s, c1d,
                                       p1w, out1b, part1);
    k_gemm2<<<(BS * NN / 64) * 2, 256, 0, stream>>>(out1b, Bb, a2, h2T, esp, edp);
    k_gat2<<<BS * H2C * 5, 256, 0, stream>>>(h2T, esp, edp, cols16, csr_len,
                                             p2w, part2);
    k_head<<<BS, 128, 0, stream>>>(xn, part1, part2, p1b, p2b, e1w, e1b,
                                   e2w, e2b, e3w, e3b, cw, cb, dout);
}

// Round 6
// 188.566 us; speedup vs baseline: 1.4243x; 1.4243x over previous
//
#include <hip/hip_runtime.h>
#include <hip/hip_bf16.h>
#include <math.h>

#define BS 128
#define NN 320
#define H1 8
#define F1 18
#define D1 144
#define H2C 4
#define F2 46
#define FC0 104
#define FC1 45
#define FC2 84
#define LRA 0.2f
#define DEGCAP 96

typedef __attribute__((ext_vector_type(8))) short bf16x8;
typedef __attribute__((ext_vector_type(4))) float f32x4;

__device__ __forceinline__ float wave_max64(float v) {
    #pragma unroll
    for (int off = 32; off > 0; off >>= 1)
        v = fmaxf(v, __shfl_xor(v, off, 64));
    return v;
}
__device__ __forceinline__ float wave_sum64(float v) {
    #pragma unroll
    for (int off = 32; off > 0; off >>= 1)
        v += __shfl_xor(v, off, 64);
    return v;
}
__device__ __forceinline__ short bfb(float x) {
    __hip_bfloat16 b = __float2bfloat16(x);
    return *(short*)&b;
}

// ---- K0: CSR build (u16, fwd + transposed, lo/hi split) + consts + Bb ------
__global__ void k_csr(const float* __restrict__ adj,
                      unsigned short* __restrict__ cols16,
                      unsigned short* __restrict__ colsT16,
                      int* __restrict__ len, int* __restrict__ llo,
                      const float* __restrict__ W1,
                      const float* __restrict__ a1, float* __restrict__ c1s,
                      float* __restrict__ c1d, const float* __restrict__ W2,
                      __hip_bfloat16* __restrict__ Bb) {
    int row = blockIdx.x;
    int lane = threadIdx.x;  // 64 threads
    if (row < NN) {
        int base = 0, lo = 0;
        for (int c0 = 0; c0 < NN; c0 += 64) {
            int j = c0 + lane;
            bool p = (j < NN) && (adj[row * NN + j] > 0.f);
            unsigned long long m = __ballot(p);
            if (p) {
                int pos = base + __popcll(m & ((1ull << lane) - 1ull));
                if (pos < DEGCAP) {
                    cols16[row * DEGCAP + pos] = (unsigned short)j;
                    colsT16[pos * NN + row] = (unsigned short)j;
                }
            }
            base += __popcll(m);
            unsigned long long mlo = __ballot(p && j < 160);
            lo += __popcll(mlo);
        }
        if (base > DEGCAP) base = DEGCAP;
        if (lo > DEGCAP) lo = DEGCAP;
        for (int q = base + lane; q < DEGCAP; q += 64) {
            cols16[row * DEGCAP + q] = 0;
            colsT16[q * NN + row] = 0;
        }
        if (lane == 0) { len[row] = base; llo[row] = lo; }
    } else if (row == NN) {
        int h = lane;
        if (h < H1) {
            float s = 0.f, d = 0.f;
            for (int f = 0; f < F1; ++f) {
                float w = W1[h * F1 + f];
                s += w * a1[h * 2 * F1 + f];
                d += w * a1[h * 2 * F1 + F1 + f];
            }
            c1s[h] = s;
            c1d[h] = d;
        }
    } else {
        // Bb[k8][n][e]: n = h*48+f; zero pad cols f>=46 and k>=144
        int idx = (row - NN - 1) * 64 + lane;   // 0..30719
        int e = idx & 7;
        int t = idx >> 3;
        int n = t % 192, k8 = t / 192;
        int k = k8 * 8 + e, hh = n / 48, f = n - hh * 48;
        float v = (k < 144 && f < 46) ? W2[(hh * 144 + k) * 46 + f] : 0.f;
        Bb[idx] = __float2bfloat16(v);
    }
}

// ---- K1: layer-1 GAT, lanes=rows, 1 head per block -------------------------
__global__ __launch_bounds__(320) void k_gat1(
    const float* __restrict__ xn, const unsigned short* __restrict__ colsT16,
    const int* __restrict__ len, const float* __restrict__ W1,
    const float* __restrict__ c1s, const float* __restrict__ c1d,
    const float* __restrict__ p1w, __hip_bfloat16* __restrict__ out1b,
    float* __restrict__ part1) {
    int b = blockIdx.x >> 3, h = blockIdx.x & 7;
    __shared__ float xb[NN], stab[NN];
    __shared__ float w1h[F1], pwl[F1];
    __shared__ float redmax[5], redmin[5];
    int tid = threadIdx.x;          // == row
    int wv = tid >> 6, lane = tid & 63;
    float xi = xn[b * NN + tid];
    xb[tid] = xi;
    if (tid < F1) { w1h[tid] = W1[h * F1 + tid]; pwl[tid] = p1w[h * F1 + tid]; }
    int Li = len[tid];
    float mx = wave_max64(xi);
    float mn = -wave_max64(-xi);
    int Lmax = (int)wave_max64((float)Li);
    if (lane == 0) { redmax[wv] = mx; redmin[wv] = mn; }
    __syncthreads();
    float MX = redmax[0], MN = redmin[0];
    #pragma unroll
    for (int q = 1; q < 5; ++q) {
        MX = fmaxf(MX, redmax[q]);
        MN = fminf(MN, redmin[q]);
    }
    float cs = c1s[h], cd = c1d[h];
    float u = xi * cs;
    float mt = u + (cd > 0.f ? cd * MX : cd * MN);
    float m = fmaxf(mt, LRA * mt);
    float num = 0.f, den = 0.f;
    const unsigned short* ct = colsT16 + tid;
    int colv = ct[0];
    for (int j = 0; j < Lmax; ++j) {
        int coln = (j + 1 < Lmax) ? ct[(j + 1) * NN] : 0;
        float xj = xb[colv];
        bool act = j < Li;
        float t = fmaf(xj, cd, u);
        t = fmaxf(t, LRA * t);
        float w = __expf(t - m);
        w = act ? w : 0.f;
        num = fmaf(w, xj, num);
        den += w;
        colv = coln;
    }
    stab[tid] = num / den;
    __syncthreads();
    // write this head's 18 columns (+pads if h==0)
    for (int idx = tid; idx < NN * F1; idx += 320) {
        int row = idx / F1, c = idx - row * F1;
        float v = stab[row] * w1h[c];
        v = v > 0.f ? v : expm1f(v);
        out1b[(size_t)(b * NN + row) * 160 + h * F1 + c] = __float2bfloat16(v);
    }
    if (h == 0) {
        for (int idx = tid; idx < NN * 16; idx += 320) {
            int row = idx >> 4, c = idx & 15;
            out1b[(size_t)(b * NN + row) * 160 + 144 + c] = __float2bfloat16(0.f);
        }
    }
    float part = 0.f;
    float s = stab[tid];
    #pragma unroll
    for (int f = 0; f < F1; ++f) {
        float v = s * w1h[f];
        v = v > 0.f ? v : expm1f(v);
        part = fmaf(v, pwl[f], part);
    }
    part1[(size_t)(b * 8 + h) * NN + tid] = part;
}

// ---- K3: h2T = (out1 @ W2)^T via bf16 MFMA + es/ed partial epilogue --------
__global__ __launch_bounds__(256) void k_gemm2(
    const __hip_bfloat16* __restrict__ A,    // [40960][160] bf16
    const __hip_bfloat16* __restrict__ Bb,   // [20][192][8] bf16
    const float* __restrict__ a2,
    __hip_bfloat16* __restrict__ h2T,        // [512][48][320]
    float* __restrict__ esp, float* __restrict__ edp) {  // [2][512][320]
    __shared__ __align__(16) __hip_bfloat16 As[64 * 168];
    __shared__ __align__(16) __hip_bfloat16 Bs[20 * 96 * 8];
    __shared__ float a2e[4][48], a2d[4][48];
    int tid = threadIdx.x;
    int mblk = blockIdx.x >> 1, hblk = blockIdx.x & 1;
    int r0 = mblk * 64;
    const uint4* Ag = (const uint4*)(A + (size_t)r0 * 160);
    for (int q = tid; q < 1280; q += 256) {
        int row = q / 20, k8 = q % 20;
        *(uint4*)(As + row * 168 + k8 * 8) = Ag[q];
    }
    const uint4* Bg = (const uint4*)Bb;
    for (int q = tid; q < 1920; q += 256) {
        int k8 = q / 96, nl = q % 96;
        *(uint4*)(Bs + (k8 * 96 + nl) * 8) = Bg[k8 * 192 + hblk * 96 + nl];
    }
    if (tid < 192) {
        int hh = tid / 48, f = tid - hh * 48;
        a2e[hh][f] = f < 46 ? a2[hh * 92 + f] : 0.f;
        a2d[hh][f] = f < 46 ? a2[hh * 92 + 46 + f] : 0.f;
    }
    __syncthreads();
    int wv = tid >> 6, l = tid & 63;
    int lr = l & 15, lq = l >> 4;
    bf16x8 af[5];
    const __hip_bfloat16* arow = As + (wv * 16 + lr) * 168 + lq * 8;
    #pragma unroll
    for (int kc = 0; kc < 5; ++kc)
        af[kc] = *(const bf16x8*)(arow + kc * 32);
    f32x4 acc[6];
    #pragma unroll
    for (int t = 0; t < 6; ++t) acc[t] = (f32x4){0.f, 0.f, 0.f, 0.f};
    #pragma unroll
    for (int t = 0; t < 6; ++t) {
        const __hip_bfloat16* bcol = Bs + (t * 16 + lr) * 8;
        #pragma unroll
        for (int kc = 0; kc < 5; ++kc) {
            bf16x8 bf = *(const bf16x8*)(bcol + (kc * 4 + lq) * 768);
            acc[t] = __builtin_amdgcn_mfma_f32_16x16x32_bf16(af[kc], bf, acc[t], 0, 0, 0);
        }
    }
    int b = r0 / NN;
    int nbase = (r0 % NN) + wv * 16 + lq * 4;
    #pragma unroll
    for (int t = 0; t < 6; ++t) {
        int hh = 2 * hblk + (t >= 3);
        int f = (t % 3) * 16 + lr;
        short4 s4;
        s4.x = bfb(acc[t][0]); s4.y = bfb(acc[t][1]);
        s4.z = bfb(acc[t][2]); s4.w = bfb(acc[t][3]);
        *(short4*)(h2T + ((size_t)(b * 4 + hh) * 48 + f) * NN + nbase) = s4;
    }
    float esa[2][4], eda[2][4];
    #pragma unroll
    for (int hs = 0; hs < 2; ++hs)
        #pragma unroll
        for (int j = 0; j < 4; ++j) { esa[hs][j] = 0.f; eda[hs][j] = 0.f; }
    #pragma unroll
    for (int t = 0; t < 6; ++t) {
        int hs = (t >= 3);
        int hh = 2 * hblk + hs;
        int f = (t % 3) * 16 + lr;
        float ae = a2e[hh][f], ad = a2d[hh][f];
        #pragma unroll
        for (int j = 0; j < 4; ++j) {
            esa[hs][j] = fmaf(acc[t][j], ae, esa[hs][j]);
            eda[hs][j] = fmaf(acc[t][j], ad, eda[hs][j]);
        }
    }
    #pragma unroll
    for (int hs = 0; hs < 2; ++hs)
        #pragma unroll
        for (int j = 0; j < 4; ++j) {
            #pragma unroll
            for (int off = 1; off < 16; off <<= 1) {
                esa[hs][j] += __shfl_xor(esa[hs][j], off, 64);
                eda[hs][j] += __shfl_xor(eda[hs][j], off, 64);
            }
        }
    if (lr == 0) {
        #pragma unroll
        for (int hs = 0; hs < 2; ++hs) {
            int bh = b * 4 + 2 * hblk + hs;
            #pragma unroll
            for (int j = 0; j < 4; ++j) {
                esp[(size_t)hblk * 512 * NN + (size_t)bh * NN + nbase + j] = esa[hs][j];
                edp[(size_t)hblk * 512 * NN + (size_t)bh * NN + nbase + j] = eda[hs][j];
            }
        }
    }
}

// ---- K4: layer-2 GAT: sparse P-fill + MFMA, K split into two LDS passes ----
// grid: bx = tile*512 + bh (same-bh tiles land on same XCD for H reuse).
__global__ __launch_bounds__(256) void k_gat2(
    const __hip_bfloat16* __restrict__ h2T,  // [512][48][320]
    const float* __restrict__ esp, const float* __restrict__ edp,
    const unsigned short* __restrict__ cols16, const int* __restrict__ len,
    const int* __restrict__ llo,
    const float* __restrict__ p2w, float* __restrict__ part2) {
    int bx = blockIdx.x;
    int bh = bx & 511, tile = bx >> 9;
    int h = bh & 3;
    int r0 = tile * 64;
    __shared__ __align__(16) __hip_bfloat16 P[64][168];       // 21504 B
    __shared__ __align__(16) __hip_bfloat16 Hs[48][168];      // 16128 B
    __shared__ __align__(16) unsigned short colsL[64][DEGCAP];// 12288 B
    __shared__ float esl[64], denl[64], edl[NN];
    __shared__ float pwl[48];
    __shared__ int s0l[64], s1l[64];
    __shared__ float Mred[4];
    int tid = threadIdx.x, wv = tid >> 6, lane = tid & 63;
    float edmax = -1e30f;
    for (int j = tid; j < NN; j += 256) {
        float ed = edp[(size_t)bh * NN + j] +
                   edp[(size_t)512 * NN + (size_t)bh * NN + j];
        edl[j] = ed;
        edmax = fmaxf(edmax, ed);
    }
    if (tid < 64) {
        esl[tid] = esp[(size_t)bh * NN + r0 + tid] +
                   esp[(size_t)512 * NN + (size_t)bh * NN + r0 + tid];
        s0l[tid] = llo[r0 + tid];
        s1l[tid] = len[r0 + tid];
    }
    if (tid < 48) pwl[tid] = tid < 46 ? p2w[h * F2 + tid] : 0.f;
    // stage cols for the 64 rows (768 uint4)
    const uint4* cg = (const uint4*)(cols16 + (size_t)r0 * DEGCAP);
    for (int q = tid; q < 768; q += 256) ((uint4*)&colsL[0][0])[q] = cg[q];
    float wm = wave_max64(edmax);
    if (lane == 0) Mred[wv] = wm;
    __syncthreads();
    float M = fmaxf(fmaxf(Mred[0], Mred[1]), fmaxf(Mred[2], Mred[3]));
    int lr = lane & 15, lq = lane >> 4;
    int r = lane & 15, e = lane >> 4;
    int row = wv * 16 + r;
    float es = esl[row];
    float t0 = es + M;
    float m = fmaxf(t0, LRA * t0);
    f32x4 acc[3];
    #pragma unroll
    for (int t = 0; t < 3; ++t) acc[t] = (f32x4){0.f, 0.f, 0.f, 0.f};
    for (int p = 0; p < 2; ++p) {
        if (p) __syncthreads();   // previous phase-2 done reading P/Hs
        // zero P-half + stage H-half
        for (int q = tid; q < 1344; q += 256)
            ((uint4*)&P[0][0])[q] = (uint4){0u, 0u, 0u, 0u};
        for (int q = tid; q < 960; q += 256) {
            int f = q / 20, c = q - f * 20;
            *(uint4*)(&Hs[f][c * 8]) =
                *(const uint4*)(h2T + ((size_t)bh * 48 + f) * NN + p * 160 + c * 8);
        }
        __syncthreads();
        // phase 1: fill P-half (16 rows x 4 edge-slots per wave)
        int s0 = p ? s0l[row] : 0;
        int s1 = p ? s1l[row] : s0l[row];
        int pofs = p * 160;
        float dp = 0.f;
        for (int j = s0 + e; j < s1; j += 4) {
            int col = colsL[row][j];
            float t = es + edl[col];
            t = fmaxf(t, LRA * t);
            float w = __expf(t - m);
            dp += w;
            P[row][col - pofs] = __float2bfloat16(w);
        }
        dp += __shfl_xor(dp, 16, 64);
        dp += __shfl_xor(dp, 32, 64);
        if (e == 0) { if (p) denl[row] += dp; else denl[row] = dp; }
        // no barrier needed: wave wv wrote exactly P rows wv*16..wv*16+15,
        // which are the only rows its MFMA A-fragments read.
        const __hip_bfloat16* Arow = &P[wv * 16 + lr][lq * 8];
        #pragma unroll
        for (int k = 0; k < 5; ++k) {
            bf16x8 a = *(const bf16x8*)(Arow + k * 32);
            #pragma unroll
            for (int t = 0; t < 3; ++t) {
                bf16x8 bf = *(const bf16x8*)(&Hs[t * 16 + lr][k * 32 + lq * 8]);
                acc[t] = __builtin_amdgcn_mfma_f32_16x16x32_bf16(a, bf, acc[t], 0, 0, 0);
            }
        }
    }
    // epilogue
    float inv[4], part[4];
    #pragma unroll
    for (int j = 0; j < 4; ++j) {
        inv[j] = 1.f / denl[wv * 16 + lq * 4 + j];
        part[j] = 0.f;
    }
    #pragma unroll
    for (int t = 0; t < 3; ++t) {
        float pw = pwl[t * 16 + lr];
        #pragma unroll
        for (int j = 0; j < 4; ++j) {
            float v = acc[t][j] * inv[j];
            v = v > 0.f ? v : expm1f(v);
            part[j] = fmaf(v, pw, part[j]);
        }
    }
    #pragma unroll
    for (int j = 0; j < 4; ++j) {
        #pragma unroll
        for (int off = 1; off < 16; off <<= 1)
            part[j] += __shfl_xor(part[j], off, 64);
    }
    if (lr == 0) {
        #pragma unroll
        for (int j = 0; j < 4; ++j)
            part2[(size_t)bh * NN + r0 + wv * 16 + lq * 4 + j] = part[j];
    }
}

// ---- K5: x_concat assembly + FC head ---------------------------------------
__global__ __launch_bounds__(256) void k_head(
    const float* __restrict__ xn, const float* __restrict__ part1,
    const float* __restrict__ part2, const float* __restrict__ p1b,
    const float* __restrict__ p2b, const float* __restrict__ e1w,
    const float* __restrict__ e1b, const float* __restrict__ e2w,
    const float* __restrict__ e2b, const float* __restrict__ e3w,
    const float* __restrict__ e3b, const float* __restrict__ cw,
    const float* __restrict__ cb, float* __restrict__ dout) {
    int b = blockIdx.x;
    int tid = threadIdx.x;
    __shared__ float xc[960];
    __shared__ float e1part[2][FC0];
    __shared__ float h1[FC0];
    __shared__ float hh[FC1];
    __shared__ float ft[FC2];
    for (int t = tid; t < NN; t += 256) {
        float x0 = xn[b * NN + t];
        xc[t] = x0;
        dout[b * 960 + t] = x0;
        float s1 = p1b[0];
        #pragma unroll
        for (int h = 0; h < 8; ++h) s1 += part1[(size_t)(b * 8 + h) * NN + t];
        xc[320 + t] = s1;
        dout[b * 960 + 320 + t] = s1;
        float s2 = p2b[0];
        #pragma unroll
        for (int h = 0; h < 4; ++h) s2 += part2[(size_t)(b * 4 + h) * NN + t];
        xc[640 + t] = s2;
        dout[b * 960 + 640 + t] = s2;
    }
    __syncthreads();
    {
        int half = tid >> 7, o = tid & 127;
        if (o < FC0) {
            float a = 0.f;
            int k0 = half * 480;
            for (int k = k0; k < k0 + 480; ++k)
                a = fmaf(xc[k], e1w[k * FC0 + o], a);
            e1part[half][o] = a;
        }
    }
    __syncthreads();
    if (tid < FC0) {
        float a = e1b[tid] + e1part[0][tid] + e1part[1][tid];
        h1[tid] = a > 0.f ? a : expm1f(a);
    }
    __syncthreads();
    if (tid < FC1) {
        float a = e2b[tid];
        for (int k = 0; k < FC0; ++k) a += h1[k] * e2w[k * FC1 + tid];
        hh[tid] = a > 0.f ? a : expm1f(a);
    }
    __syncthreads();
    if (tid < FC2) {
        float a = e3b[tid];
        for (int k = 0; k < FC1; ++k) a += hh[k] * e3w[k * FC2 + tid];
        a = a > 0.f ? a : expm1f(a);
        ft[tid] = a;
        dout[BS * 960 + b * FC2 + tid] = a;
    }
    __syncthreads();
    if (tid < 64) {
        float v = 0.f;
        for (int t = tid; t < FC2; t += 64) v += ft[t] * cw[t];
        v = wave_sum64(v);
        if (tid == 0) dout[BS * 960 + BS * FC2 + b] = v + cb[0];
    }
}

extern "C" void kernel_launch(void* const* d_in, const int* in_sizes, int n_in,
                              void* d_out, int out_size, void* d_ws,
                              size_t ws_size, hipStream_t stream) {
    const float* xn  = (const float*)d_in[0];
    const float* adj = (const float*)d_in[1];
    const float* W1  = (const float*)d_in[2];
    const float* a1  = (const float*)d_in[3];
    const float* W2  = (const float*)d_in[4];
    const float* a2  = (const float*)d_in[5];
    const float* p1w = (const float*)d_in[6];
    const float* p1b = (const float*)d_in[7];
    const float* p2w = (const float*)d_in[8];
    const float* p2b = (const float*)d_in[9];
    const float* e1w = (const float*)d_in[10];
    const float* e1b = (const float*)d_in[11];
    const float* e2w = (const float*)d_in[12];
    const float* e2b = (const float*)d_in[13];
    const float* e3w = (const float*)d_in[14];
    const float* e3b = (const float*)d_in[15];
    const float* cw  = (const float*)d_in[16];
    const float* cb  = (const float*)d_in[17];

    char* ws = (char*)d_ws;
    int*   csr_len  = (int*)ws;                                // 1280
    int*   csr_llo  = (int*)(ws + 1280);                       // 1280 -> 2560
    float* c1s      = (float*)(ws + 2560);                     // 32
    float* c1d      = (float*)(ws + 2592);                     // 32 (pad->2688)
    unsigned short* cols16  = (unsigned short*)(ws + 2688);    // 61440 -> 64128
    unsigned short* colsT16 = (unsigned short*)(ws + 64128);   // 61440 -> 125568
    __hip_bfloat16* Bb    = (__hip_bfloat16*)(ws + 125568);    // 61440 -> 187008
    __hip_bfloat16* out1b = (__hip_bfloat16*)(ws + 187008);    // 13107200 -> 13294208
    __hip_bfloat16* h2T   = (__hip_bfloat16*)(ws + 13294208);  // 15728640 -> 29022848
    float* esp      = (float*)(ws + 29022848);                 // 1310720 -> 30333568
    float* edp      = (float*)(ws + 30333568);                 // 1310720 -> 31644288
    float* part1    = (float*)(ws + 31644288);                 // 1310720 -> 32955008
    float* part2    = (float*)(ws + 32955008);                 // 655360 -> 33610368
    float* dout     = (float*)d_out;

    k_csr<<<NN + 1 + 480, 64, 0, stream>>>(adj, cols16, colsT16, csr_len,
                                           csr_llo, W1, a1, c1s, c1d, W2, Bb);
    k_gat1<<<BS * H1, 320, 0, stream>>>(xn, colsT16, csr_len, W1, c1s, c1d,
                                        p1w, out1b, part1);
    k_gemm2<<<(BS * NN / 64) * 2, 256, 0, stream>>>(out1b, Bb, a2, h2T, esp, edp);
    k_gat2<<<5 * 512, 256, 0, stream>>>(h2T, esp, edp, cols16, csr_len,
                                        csr_llo, p2w, part2);
    k_head<<<BS, 256, 0, stream>>>(xn, part1, part2, p1b, p2b, e1w, e1b,
                                   e2w, e2b, e3w, e3b, cw, cb, dout);
}

// Round 7
// 181.521 us; speedup vs baseline: 1.4796x; 1.0388x over previous
//
#include <hip/hip_runtime.h>
#include <hip/hip_bf16.h>
#include <math.h>

#define BS 128
#define NN 320
#define H1 8
#define F1 18
#define H2C 4
#define F2 46
#define FC0 104
#define FC1 45
#define FC2 84
#define LRA 0.2f
#define DEGCAP 96
#define PW 104   // P/As row stride in bf16 (208 B: 16B-aligned, 52 dw = 2-way banks)

typedef __attribute__((ext_vector_type(8))) short bf16x8;
typedef __attribute__((ext_vector_type(4))) float f32x4;

__device__ __forceinline__ float wave_max64(float v) {
    #pragma unroll
    for (int off = 32; off > 0; off >>= 1)
        v = fmaxf(v, __shfl_xor(v, off, 64));
    return v;
}
__device__ __forceinline__ short bfb(float x) {
    __hip_bfloat16 b = __float2bfloat16(x);
    return *(short*)&b;
}

// ---- K0: CSR build (fwd u16 + transposed u16 + seg meta) + consts + Bb -----
__global__ void k_csr(const float* __restrict__ adj,
                      unsigned short* __restrict__ cols16,
                      unsigned short* __restrict__ colsT16,
                      int4* __restrict__ meta, const float* __restrict__ W1,
                      const float* __restrict__ a1, float* __restrict__ c1s,
                      float* __restrict__ c1d, const float* __restrict__ W2,
                      __hip_bfloat16* __restrict__ Bb) {
    int row = blockIdx.x;
    int lane = threadIdx.x;  // 64 threads
    if (row < NN) {
        int base = 0, c96 = 0, c192 = 0, c288 = 0;
        for (int c0 = 0; c0 < NN; c0 += 64) {
            int j = c0 + lane;
            bool p = (j < NN) && (adj[row * NN + j] > 0.f);
            unsigned long long m = __ballot(p);
            if (p) {
                int pos = base + __popcll(m & ((1ull << lane) - 1ull));
                if (pos < DEGCAP) {
                    cols16[row * DEGCAP + pos] = (unsigned short)j;
                    colsT16[pos * NN + row] = (unsigned short)j;
                }
            }
            base += __popcll(m);
            c96  += __popcll(__ballot(p && j < 96));
            c192 += __popcll(__ballot(p && j < 192));
            c288 += __popcll(__ballot(p && j < 288));
        }
        if (base > DEGCAP) base = DEGCAP;
        if (c96 > DEGCAP) c96 = DEGCAP;
        if (c192 > DEGCAP) c192 = DEGCAP;
        if (c288 > DEGCAP) c288 = DEGCAP;
        for (int q = base + lane; q < DEGCAP; q += 64) {
            cols16[row * DEGCAP + q] = 0;
            colsT16[q * NN + row] = 0;
        }
        if (lane == 0) meta[row] = make_int4(c96, c192, c288, base);
    } else if (row == NN) {
        int h = lane;
        if (h < H1) {
            float s = 0.f, d = 0.f;
            for (int f = 0; f < F1; ++f) {
                float w = W1[h * F1 + f];
                s += w * a1[h * 2 * F1 + f];
                d += w * a1[h * 2 * F1 + F1 + f];
            }
            c1s[h] = s;
            c1d[h] = d;
        }
    } else {
        // Bb[k8][n][e]: n = h*48+f; zero pad cols f>=46 and k>=144
        int idx = (row - NN - 1) * 64 + lane;   // 0..30719
        int e = idx & 7;
        int t = idx >> 3;
        int n = t % 192, k8 = t / 192;
        int k = k8 * 8 + e, hh = n / 48, f = n - hh * 48;
        float v = (k < 144 && f < 46) ? W2[(hh * 144 + k) * 46 + f] : 0.f;
        Bb[idx] = __float2bfloat16(v);
    }
}

// ---- K1: layer-1 GAT, lanes=rows -> s scalars + pool1 partials -------------
__global__ __launch_bounds__(320) void k_l1(
    const float* __restrict__ xn, const unsigned short* __restrict__ colsT16,
    const int4* __restrict__ meta, const float* __restrict__ W1,
    const float* __restrict__ c1s, const float* __restrict__ c1d,
    const float* __restrict__ p1w, float* __restrict__ sg,
    float* __restrict__ part1) {
    int b = blockIdx.x >> 3, h = blockIdx.x & 7;
    __shared__ float xb[NN];
    __shared__ float w1h[F1], pwl[F1];
    __shared__ float redmax[5], redmin[5];
    int tid = threadIdx.x;          // == row
    int wv = tid >> 6, lane = tid & 63;
    float xi = xn[b * NN + tid];
    xb[tid] = xi;
    if (tid < F1) { w1h[tid] = W1[h * F1 + tid]; pwl[tid] = p1w[h * F1 + tid]; }
    int Li = meta[tid].w;
    float mx = wave_max64(xi);
    float mn = -wave_max64(-xi);
    int Lmax = (int)wave_max64((float)Li);
    if (lane == 0) { redmax[wv] = mx; redmin[wv] = mn; }
    __syncthreads();
    float MX = redmax[0], MN = redmin[0];
    #pragma unroll
    for (int q = 1; q < 5; ++q) {
        MX = fmaxf(MX, redmax[q]);
        MN = fminf(MN, redmin[q]);
    }
    float cs = c1s[h], cd = c1d[h];
    float u = xi * cs;
    float mt = u + (cd > 0.f ? cd * MX : cd * MN);
    float m = fmaxf(mt, LRA * mt);
    float num = 0.f, den = 0.f;
    const unsigned short* ct = colsT16 + tid;
    int colv = ct[0];
    for (int j = 0; j < Lmax; ++j) {
        int coln = (j + 1 < Lmax) ? ct[(j + 1) * NN] : 0;
        float xj = xb[colv];
        bool act = j < Li;
        float t = fmaf(xj, cd, u);
        t = fmaxf(t, LRA * t);
        float w = __expf(t - m);
        w = act ? w : 0.f;
        num = fmaf(w, xj, num);
        den += w;
        colv = coln;
    }
    float s = num / den;
    sg[(size_t)(b * 8 + h) * NN + tid] = s;
    float part = 0.f;
    #pragma unroll
    for (int f = 0; f < F1; ++f) {
        float v = s * w1h[f];
        v = v > 0.f ? v : expm1f(v);
        part = fmaf(v, pwl[f], part);
    }
    part1[(size_t)(b * 8 + h) * NN + tid] = part;
}

// ---- K2: fused layer-2: A-build + GEMM + es/ed + P-fill + P@H + pool -------
// One block per (b, h2). 2 barriers total; all tile work is wave-local.
__global__ __launch_bounds__(256) void k_l2(
    const float* __restrict__ sg, const unsigned short* __restrict__ cols16,
    const int4* __restrict__ meta, const __hip_bfloat16* __restrict__ Bb,
    const float* __restrict__ W1, const float* __restrict__ a2,
    const float* __restrict__ p2w, float* __restrict__ part2) {
    int bh = blockIdx.x;
    int b = bh >> 2, h = bh & 3;
    __shared__ __align__(16) __hip_bfloat16 HT[48][328];          // 31488 B
    __shared__ __align__(16) __hip_bfloat16 AsP[4][16][PW];       // 13312 B
    __shared__ __align__(16) unsigned short colsW[4][16][DEGCAP]; // 12288 B
    __shared__ float sglW[4][8][16];                              // 2048 B
    __shared__ float esl[NN], edl[NN];                            // 2560 B
    __shared__ float denW[4][16];                                 // 256 B
    __shared__ float w1l[8][F1];                                  // 576 B
    __shared__ float pwl[48], a2e[48], a2d[48];                   // 576 B
    __shared__ float Mred[4];                                     // 16 B
    int tid = threadIdx.x, wv = tid >> 6, lane = tid & 63;
    int lr = lane & 15, lq = lane >> 4;
    if (tid < 48) {
        pwl[tid] = tid < 46 ? p2w[h * F2 + tid] : 0.f;
        a2e[tid] = tid < 46 ? a2[h * 92 + tid] : 0.f;
        a2d[tid] = tid < 46 ? a2[h * 92 + 46 + tid] : 0.f;
    }
    if (tid < 144) {
        int hh = tid / F1, f = tid - hh * F1;
        w1l[hh][f] = W1[hh * F1 + f];
    }
    // B-fragments in registers (tile-invariant)
    bf16x8 bq[5][3];
    #pragma unroll
    for (int kc = 0; kc < 5; ++kc)
        #pragma unroll
        for (int t = 0; t < 3; ++t)
            bq[kc][t] = *(const bf16x8*)(Bb +
                (size_t)(((kc * 4 + lq) * 192) + h * 48 + t * 16 + lr) * 8);
    __syncthreads();
    // ---------------- phase 1: H = A @ B, HT/es/ed to LDS ----------------
    for (int tile = 0; tile < 5; ++tile) {
        int r0 = tile * 64;
        for (int q = lane; q < 128; q += 64) {
            int hh = q >> 4, row = q & 15;
            sglW[wv][hh][row] = sg[(size_t)(b * 8 + hh) * NN + r0 + wv * 16 + row];
        }
        f32x4 acc[3];
        #pragma unroll
        for (int t = 0; t < 3; ++t) acc[t] = (f32x4){0.f, 0.f, 0.f, 0.f};
        #pragma unroll
        for (int sp = 0; sp < 2; ++sp) {
            const int nch = sp ? 2 : 3;
            #pragma unroll
            for (int j = 0; j < nch; ++j) {
                int chunk = (sp ? 12 : 0) + lq + 4 * j;
                int cb = chunk * 8;
                bf16x8 pv;
                #pragma unroll
                for (int e = 0; e < 8; ++e) {
                    unsigned c = cb + e;
                    float v = 0.f;
                    if (c < 144) {
                        unsigned hh = c / 18, f = c - hh * 18;
                        v = sglW[wv][hh][lr] * w1l[hh][f];
                        v = v > 0.f ? v : expm1f(v);
                    }
                    pv[e] = bfb(v);
                }
                *(bf16x8*)&AsP[wv][lr][cb - sp * 96] = pv;
            }
            const int nkc = sp ? 2 : 3;
            #pragma unroll
            for (int kc2 = 0; kc2 < nkc; ++kc2) {
                bf16x8 a = *(const bf16x8*)&AsP[wv][lr][kc2 * 32 + lq * 8];
                int gkc = sp ? 3 + kc2 : kc2;
                #pragma unroll
                for (int t = 0; t < 3; ++t)
                    acc[t] = __builtin_amdgcn_mfma_f32_16x16x32_bf16(
                        a, bq[gkc][t], acc[t], 0, 0, 0);
            }
        }
        int node = r0 + wv * 16 + lq * 4;
        #pragma unroll
        for (int t = 0; t < 3; ++t) {
            short4 s4;
            s4.x = bfb(acc[t][0]); s4.y = bfb(acc[t][1]);
            s4.z = bfb(acc[t][2]); s4.w = bfb(acc[t][3]);
            *(short4*)&HT[t * 16 + lr][node] = s4;
        }
        float esa[4] = {0.f, 0.f, 0.f, 0.f}, eda[4] = {0.f, 0.f, 0.f, 0.f};
        #pragma unroll
        for (int t = 0; t < 3; ++t) {
            float ae = a2e[t * 16 + lr], ad = a2d[t * 16 + lr];
            #pragma unroll
            for (int j = 0; j < 4; ++j) {
                esa[j] = fmaf(acc[t][j], ae, esa[j]);
                eda[j] = fmaf(acc[t][j], ad, eda[j]);
            }
        }
        #pragma unroll
        for (int j = 0; j < 4; ++j) {
            #pragma unroll
            for (int off = 1; off < 16; off <<= 1) {
                esa[j] += __shfl_xor(esa[j], off, 64);
                eda[j] += __shfl_xor(eda[j], off, 64);
            }
        }
        if (lr == 0) {
            #pragma unroll
            for (int j = 0; j < 4; ++j) {
                esl[node + j] = esa[j];
                edl[node + j] = eda[j];
            }
        }
    }
    __syncthreads();   // HT/esl/edl complete
    float edmax = -1e30f;
    for (int i = tid; i < NN; i += 256) edmax = fmaxf(edmax, edl[i]);
    float wm = wave_max64(edmax);
    if (lane == 0) Mred[wv] = wm;
    __syncthreads();
    float M = fmaxf(fmaxf(Mred[0], Mred[1]), fmaxf(Mred[2], Mred[3]));
    // ---------------- phase 2: P-fill + P@H + pool ----------------
    for (int tile = 0; tile < 5; ++tile) {
        int r0 = tile * 64;
        for (int q = lane; q < 192; q += 64) {
            int rr = q / 12, c8 = q - rr * 12;
            *(uint4*)&colsW[wv][rr][c8 * 8] =
                *(const uint4*)(cols16 + (size_t)(r0 + wv * 16 + rr) * DEGCAP + c8 * 8);
        }
        int i = r0 + wv * 16 + lr;
        int4 mt = meta[i];
        int sb0 = mt.x, sb1 = mt.y, sb2 = mt.z, sb3 = mt.w;
        float es = esl[i];
        float t0 = es + M;
        float m = fmaxf(t0, LRA * t0);
        f32x4 acc[3];
        #pragma unroll
        for (int t = 0; t < 3; ++t) acc[t] = (f32x4){0.f, 0.f, 0.f, 0.f};
        float dp = 0.f;
        #pragma unroll
        for (int pass = 0; pass < 4; ++pass) {
            for (int q = lane; q < 208; q += 64) {
                int rr = q / 13, cc = q - rr * 13;
                *(uint4*)&AsP[wv][rr][cc * 8] = (uint4){0u, 0u, 0u, 0u};
            }
            int s0 = pass == 0 ? 0 : (pass == 1 ? sb0 : (pass == 2 ? sb1 : sb2));
            int s1 = pass == 0 ? sb0 : (pass == 1 ? sb1 : (pass == 2 ? sb2 : sb3));
            int pofs = pass * 96;
            for (int j = s0 + lq; j < s1; j += 4) {
                int col = colsW[wv][lr][j];
                float t = es + edl[col];
                t = fmaxf(t, LRA * t);
                float w = __expf(t - m);
                dp += w;
                AsP[wv][lr][col - pofs] = __float2bfloat16(w);
            }
            const int nkf = (pass < 3) ? 3 : 1;
            #pragma unroll
            for (int kf = 0; kf < nkf; ++kf) {
                bf16x8 a = *(const bf16x8*)&AsP[wv][lr][kf * 32 + lq * 8];
                #pragma unroll
                for (int t = 0; t < 3; ++t) {
                    bf16x8 bb = *(const bf16x8*)&HT[t * 16 + lr][pofs + kf * 32 + lq * 8];
                    acc[t] = __builtin_amdgcn_mfma_f32_16x16x32_bf16(
                        a, bb, acc[t], 0, 0, 0);
                }
            }
        }
        dp += __shfl_xor(dp, 16, 64);
        dp += __shfl_xor(dp, 32, 64);
        if (lq == 0) denW[wv][lr] = dp;
        float inv[4], part[4];
        #pragma unroll
        for (int j = 0; j < 4; ++j) {
            inv[j] = 1.f / denW[wv][lq * 4 + j];
            part[j] = 0.f;
        }
        #pragma unroll
        for (int t = 0; t < 3; ++t) {
            float pw = pwl[t * 16 + lr];
            #pragma unroll
            for (int j = 0; j < 4; ++j) {
                float v = acc[t][j] * inv[j];
                v = v > 0.f ? v : expm1f(v);
                part[j] = fmaf(v, pw, part[j]);
            }
        }
        #pragma unroll
        for (int j = 0; j < 4; ++j) {
            #pragma unroll
            for (int off = 1; off < 16; off <<= 1)
                part[j] += __shfl_xor(part[j], off, 64);
        }
        if (lr == 0) {
            #pragma unroll
            for (int j = 0; j < 4; ++j)
                part2[(size_t)bh * NN + r0 + wv * 16 + lq * 4 + j] = part[j];
        }
    }
}

// ---- K3: x_concat assembly + FC head ---------------------------------------
__global__ __launch_bounds__(256) void k_head(
    const float* __restrict__ xn, const float* __restrict__ part1,
    const float* __restrict__ part2, const float* __restrict__ p1b,
    const float* __restrict__ p2b, const float* __restrict__ e1w,
    const float* __restrict__ e1b, const float* __restrict__ e2w,
    const float* __restrict__ e2b, const float* __restrict__ e3w,
    const float* __restrict__ e3b, const float* __restrict__ cw,
    const float* __restrict__ cb, float* __restrict__ dout) {
    int b = blockIdx.x;
    int tid = threadIdx.x;
    __shared__ float xc[960];
    __shared__ float e1part[2][FC0];
    __shared__ float h1[FC0];
    __shared__ float hh[FC1];
    __shared__ float ft[FC2];
    for (int t = tid; t < NN; t += 256) {
        float x0 = xn[b * NN + t];
        xc[t] = x0;
        dout[b * 960 + t] = x0;
        float s1 = p1b[0];
        #pragma unroll
        for (int h = 0; h < 8; ++h) s1 += part1[(size_t)(b * 8 + h) * NN + t];
        xc[320 + t] = s1;
        dout[b * 960 + 320 + t] = s1;
        float s2 = p2b[0];
        #pragma unroll
        for (int h = 0; h < 4; ++h) s2 += part2[(size_t)(b * 4 + h) * NN + t];
        xc[640 + t] = s2;
        dout[b * 960 + 640 + t] = s2;
    }
    __syncthreads();
    {
        int half = tid >> 7, o = tid & 127;
        if (o < FC0) {
            float a = 0.f;
            int k0 = half * 480;
            for (int k = k0; k < k0 + 480; ++k)
                a = fmaf(xc[k], e1w[k * FC0 + o], a);
            e1part[half][o] = a;
        }
    }
    __syncthreads();
    if (tid < FC0) {
        float a = e1b[tid] + e1part[0][tid] + e1part[1][tid];
        h1[tid] = a > 0.f ? a : expm1f(a);
    }
    __syncthreads();
    if (tid < FC1) {
        float a = e2b[tid];
        for (int k = 0; k < FC0; ++k) a += h1[k] * e2w[k * FC1 + tid];
        hh[tid] = a > 0.f ? a : expm1f(a);
    }
    __syncthreads();
    if (tid < FC2) {
        float a = e3b[tid];
        for (int k = 0; k < FC1; ++k) a += hh[k] * e3w[k * FC2 + tid];
        a = a > 0.f ? a : expm1f(a);
        ft[tid] = a;
        dout[BS * 960 + b * FC2 + tid] = a;
    }
    __syncthreads();
    if (tid < 64) {
        float v = 0.f;
        for (int t = tid; t < FC2; t += 64) v += ft[t] * cw[t];
        #pragma unroll
        for (int off = 32; off > 0; off >>= 1) v += __shfl_xor(v, off, 64);
        if (tid == 0) dout[BS * 960 + BS * FC2 + b] = v + cb[0];
    }
}

extern "C" void kernel_launch(void* const* d_in, const int* in_sizes, int n_in,
                              void* d_out, int out_size, void* d_ws,
                              size_t ws_size, hipStream_t stream) {
    const float* xn  = (const float*)d_in[0];
    const float* adj = (const float*)d_in[1];
    const float* W1  = (const float*)d_in[2];
    const float* a1  = (const float*)d_in[3];
    const float* W2  = (const float*)d_in[4];
    const float* a2  = (const float*)d_in[5];
    const float* p1w = (const float*)d_in[6];
    const float* p1b = (const float*)d_in[7];
    const float* p2w = (const float*)d_in[8];
    const float* p2b = (const float*)d_in[9];
    const float* e1w = (const float*)d_in[10];
    const float* e1b = (const float*)d_in[11];
    const float* e2w = (const float*)d_in[12];
    const float* e2b = (const float*)d_in[13];
    const float* e3w = (const float*)d_in[14];
    const float* e3b = (const float*)d_in[15];
    const float* cw  = (const float*)d_in[16];
    const float* cb  = (const float*)d_in[17];

    char* ws = (char*)d_ws;
    int4*  meta     = (int4*)ws;                               // 5120
    float* c1s      = (float*)(ws + 5120);                     // 32
    float* c1d      = (float*)(ws + 5152);                     // 32 (pad->5248)
    unsigned short* cols16  = (unsigned short*)(ws + 5248);    // 61440 -> 66688
    unsigned short* colsT16 = (unsigned short*)(ws + 66688);   // 61440 -> 128128
    __hip_bfloat16* Bb = (__hip_bfloat16*)(ws + 128128);       // 61440 -> 189568
    float* sg       = (float*)(ws + 189568);                   // 1310720 -> 1500288
    float* part1    = (float*)(ws + 1500288);                  // 1310720 -> 2811008
    float* part2    = (float*)(ws + 2811008);                  // 655360 -> 3466368
    float* dout     = (float*)d_out;

    k_csr<<<NN + 1 + 480, 64, 0, stream>>>(adj, cols16, colsT16, meta,
                                           W1, a1, c1s, c1d, W2, Bb);
    k_l1<<<BS * H1, 320, 0, stream>>>(xn, colsT16, meta, W1, c1s, c1d,
                                      p1w, sg, part1);
    k_l2<<<BS * H2C, 256, 0, stream>>>(sg, cols16, meta, Bb, W1, a2, p2w, part2);
    k_head<<<BS, 256, 0, stream>>>(xn, part1, part2, p1b, p2b, e1w, e1b,
                                   e2w, e2b, e3w, e3b, cw, cb, dout);
}

// Round 8
// 165.161 us; speedup vs baseline: 1.6261x; 1.0991x over previous
//
#include <hip/hip_runtime.h>
#include <hip/hip_bf16.h>
#include <math.h>

#define BS 128
#define NN 320
#define H1 8
#define F1 18
#define H2C 4
#define F2 46
#define FC0 104
#define FC1 45
#define FC2 84
#define LRA 0.2f
#define DEGCAP 96
#define PW 104   // P row stride in bf16 (208 B: 16B-aligned, 52 dw)

typedef __attribute__((ext_vector_type(8))) short bf16x8;
typedef __attribute__((ext_vector_type(4))) float f32x4;

__device__ __forceinline__ float wave_max64(float v) {
    #pragma unroll
    for (int off = 32; off > 0; off >>= 1)
        v = fmaxf(v, __shfl_xor(v, off, 64));
    return v;
}
__device__ __forceinline__ short bfb(float x) {
    __hip_bfloat16 b = __float2bfloat16(x);
    return *(short*)&b;
}

// ---- K0: CSR build (fwd u16 + transposed u16 + seg meta) + consts + Bb -----
__global__ void k_csr(const float* __restrict__ adj,
                      unsigned short* __restrict__ cols16,
                      unsigned short* __restrict__ colsT16,
                      int4* __restrict__ meta, const float* __restrict__ W1,
                      const float* __restrict__ a1, float* __restrict__ c1s,
                      float* __restrict__ c1d, const float* __restrict__ W2,
                      __hip_bfloat16* __restrict__ Bb) {
    int row = blockIdx.x;
    int lane = threadIdx.x;  // 64 threads
    if (row < NN) {
        int base = 0, c96 = 0, c192 = 0, c288 = 0;
        for (int c0 = 0; c0 < NN; c0 += 64) {
            int j = c0 + lane;
            bool p = (j < NN) && (adj[row * NN + j] > 0.f);
            unsigned long long m = __ballot(p);
            if (p) {
                int pos = base + __popcll(m & ((1ull << lane) - 1ull));
                if (pos < DEGCAP) {
                    cols16[row * DEGCAP + pos] = (unsigned short)j;
                    colsT16[pos * NN + row] = (unsigned short)j;
                }
            }
            base += __popcll(m);
            c96  += __popcll(__ballot(p && j < 96));
            c192 += __popcll(__ballot(p && j < 192));
            c288 += __popcll(__ballot(p && j < 288));
        }
        if (base > DEGCAP) base = DEGCAP;
        if (c96 > DEGCAP) c96 = DEGCAP;
        if (c192 > DEGCAP) c192 = DEGCAP;
        if (c288 > DEGCAP) c288 = DEGCAP;
        for (int q = base + lane; q < DEGCAP; q += 64) {
            cols16[row * DEGCAP + q] = 0;
            colsT16[q * NN + row] = 0;
        }
        if (lane == 0) meta[row] = make_int4(c96, c192, c288, base);
    } else if (row == NN) {
        int h = lane;
        if (h < H1) {
            float s = 0.f, d = 0.f;
            for (int f = 0; f < F1; ++f) {
                float w = W1[h * F1 + f];
                s += w * a1[h * 2 * F1 + f];
                d += w * a1[h * 2 * F1 + F1 + f];
            }
            c1s[h] = s;
            c1d[h] = d;
        }
    } else {
        // Bb[k8][n][e]: n = h*48+f; zero pad cols f>=46 and k>=144
        int idx = (row - NN - 1) * 64 + lane;   // 0..30719
        int e = idx & 7;
        int t = idx >> 3;
        int n = t % 192, k8 = t / 192;
        int k = k8 * 8 + e, hh = n / 48, f = n - hh * 48;
        float v = (k < 144 && f < 46) ? W2[(hh * 144 + k) * 46 + f] : 0.f;
        Bb[idx] = __float2bfloat16(v);
    }
}

// ---- K1: layer-1 GAT, lanes=rows -> out1b bf16 + pool1 partials ------------
__global__ __launch_bounds__(320) void k_l1(
    const float* __restrict__ xn, const unsigned short* __restrict__ colsT16,
    const int4* __restrict__ meta, const float* __restrict__ W1,
    const float* __restrict__ c1s, const float* __restrict__ c1d,
    const float* __restrict__ p1w, __hip_bfloat16* __restrict__ out1b,
    float* __restrict__ part1) {
    int b = blockIdx.x >> 3, h = blockIdx.x & 7;
    __shared__ float xb[NN];
    __shared__ float w1h[F1], pwl[F1];
    __shared__ float redmax[5], redmin[5];
    int tid = threadIdx.x;          // == row
    int wv = tid >> 6, lane = tid & 63;
    float xi = xn[b * NN + tid];
    xb[tid] = xi;
    if (tid < F1) { w1h[tid] = W1[h * F1 + tid]; pwl[tid] = p1w[h * F1 + tid]; }
    int Li = meta[tid].w;
    float mx = wave_max64(xi);
    float mn = -wave_max64(-xi);
    int Lmax = (int)wave_max64((float)Li);
    if (lane == 0) { redmax[wv] = mx; redmin[wv] = mn; }
    __syncthreads();
    float MX = redmax[0], MN = redmin[0];
    #pragma unroll
    for (int q = 1; q < 5; ++q) {
        MX = fmaxf(MX, redmax[q]);
        MN = fminf(MN, redmin[q]);
    }
    float cs = c1s[h], cd = c1d[h];
    float u = xi * cs;
    float mt = u + (cd > 0.f ? cd * MX : cd * MN);
    float m = fmaxf(mt, LRA * mt);
    float num = 0.f, den = 0.f;
    const unsigned short* ct = colsT16 + tid;
    int colv = ct[0];
    for (int j = 0; j < Lmax; ++j) {
        int coln = (j + 1 < Lmax) ? ct[(j + 1) * NN] : 0;
        float xj = xb[colv];
        bool act = j < Li;
        float t = fmaf(xj, cd, u);
        t = fmaxf(t, LRA * t);
        float w = __expf(t - m);
        w = act ? w : 0.f;
        num = fmaf(w, xj, num);
        den += w;
        colv = coln;
    }
    float s = num / den;
    // fused: elu(s*w1) -> out1b columns h*18..h*18+17, + pool partial
    float part = 0.f;
    unsigned od[9];
    #pragma unroll
    for (int f = 0; f < F1; f += 2) {
        float v0 = s * w1h[f];
        v0 = v0 > 0.f ? v0 : __expf(v0) - 1.f;
        float v1 = s * w1h[f + 1];
        v1 = v1 > 0.f ? v1 : __expf(v1) - 1.f;
        part = fmaf(v0, pwl[f], part);
        part = fmaf(v1, pwl[f + 1], part);
        od[f >> 1] = (unsigned)(unsigned short)bfb(v0) |
                     ((unsigned)(unsigned short)bfb(v1) << 16);
    }
    __hip_bfloat16* rowp = out1b + (size_t)(b * NN + tid) * 160;
    unsigned* dst = (unsigned*)(rowp + h * F1);
    #pragma unroll
    for (int q = 0; q < 9; ++q) dst[q] = od[q];
    if (h == 0) {
        uint4 z = (uint4){0u, 0u, 0u, 0u};
        *(uint4*)(rowp + 144) = z;
        *(uint4*)(rowp + 152) = z;
    }
    part1[(size_t)(b * 8 + h) * NN + tid] = part;
}

// ---- K2: fused layer-2: GEMM (A direct-from-global) + es/ed + P@H + pool ---
// One block per (b, h2). A-fragments load straight into MFMA operands.
__global__ __launch_bounds__(256) void k_l2(
    const __hip_bfloat16* __restrict__ out1b,
    const unsigned short* __restrict__ cols16,
    const int4* __restrict__ meta, const __hip_bfloat16* __restrict__ Bb,
    const float* __restrict__ a2, const float* __restrict__ p2w,
    float* __restrict__ part2) {
    int bh = blockIdx.x;
    int b = bh >> 2, h = bh & 3;
    __shared__ __align__(16) __hip_bfloat16 HT[48][328];          // 31488 B
    __shared__ __align__(16) __hip_bfloat16 AsP[4][16][PW];       // 13312 B
    __shared__ __align__(16) unsigned short colsW[4][16][DEGCAP]; // 12288 B
    __shared__ float esl[NN], edl[NN];                            // 2560 B
    __shared__ float denW[4][16];                                 // 256 B
    __shared__ float pwl[48], a2e[48], a2d[48];                   // 576 B
    __shared__ float Mred[4];                                     // 16 B
    int tid = threadIdx.x, wv = tid >> 6, lane = tid & 63;
    int lr = lane & 15, lq = lane >> 4;
    if (tid < 48) {
        pwl[tid] = tid < 46 ? p2w[h * F2 + tid] : 0.f;
        a2e[tid] = tid < 46 ? a2[h * 92 + tid] : 0.f;
        a2d[tid] = tid < 46 ? a2[h * 92 + 46 + tid] : 0.f;
    }
    // B-fragments in registers (tile-invariant)
    bf16x8 bq[5][3];
    #pragma unroll
    for (int kc = 0; kc < 5; ++kc)
        #pragma unroll
        for (int t = 0; t < 3; ++t)
            bq[kc][t] = *(const bf16x8*)(Bb +
                (size_t)(((kc * 4 + lq) * 192) + h * 48 + t * 16 + lr) * 8);
    __syncthreads();
    // ---------------- phase 1: H = A @ B, HT/es/ed to LDS ----------------
    const __hip_bfloat16* Ag = out1b + (size_t)b * NN * 160;
    for (int tile = 0; tile < 5; ++tile) {
        int r0 = tile * 64;
        const __hip_bfloat16* arow = Ag + (size_t)(r0 + wv * 16 + lr) * 160 + lq * 8;
        f32x4 acc[3];
        #pragma unroll
        for (int t = 0; t < 3; ++t) acc[t] = (f32x4){0.f, 0.f, 0.f, 0.f};
        #pragma unroll
        for (int kc = 0; kc < 5; ++kc) {
            bf16x8 a = *(const bf16x8*)(arow + kc * 32);
            #pragma unroll
            for (int t = 0; t < 3; ++t)
                acc[t] = __builtin_amdgcn_mfma_f32_16x16x32_bf16(
                    a, bq[kc][t], acc[t], 0, 0, 0);
        }
        int node = r0 + wv * 16 + lq * 4;
        #pragma unroll
        for (int t = 0; t < 3; ++t) {
            short4 s4;
            s4.x = bfb(acc[t][0]); s4.y = bfb(acc[t][1]);
            s4.z = bfb(acc[t][2]); s4.w = bfb(acc[t][3]);
            *(short4*)&HT[t * 16 + lr][node] = s4;
        }
        float esa[4] = {0.f, 0.f, 0.f, 0.f}, eda[4] = {0.f, 0.f, 0.f, 0.f};
        #pragma unroll
        for (int t = 0; t < 3; ++t) {
            float ae = a2e[t * 16 + lr], ad = a2d[t * 16 + lr];
            #pragma unroll
            for (int j = 0; j < 4; ++j) {
                esa[j] = fmaf(acc[t][j], ae, esa[j]);
                eda[j] = fmaf(acc[t][j], ad, eda[j]);
            }
        }
        #pragma unroll
        for (int j = 0; j < 4; ++j) {
            #pragma unroll
            for (int off = 1; off < 16; off <<= 1) {
                esa[j] += __shfl_xor(esa[j], off, 64);
                eda[j] += __shfl_xor(eda[j], off, 64);
            }
        }
        if (lr == 0) {
            #pragma unroll
            for (int j = 0; j < 4; ++j) {
                esl[node + j] = esa[j];
                edl[node + j] = eda[j];
            }
        }
    }
    __syncthreads();   // HT/esl/edl complete
    float edmax = -1e30f;
    for (int i = tid; i < NN; i += 256) edmax = fmaxf(edmax, edl[i]);
    float wm = wave_max64(edmax);
    if (lane == 0) Mred[wv] = wm;
    __syncthreads();
    float M = fmaxf(fmaxf(Mred[0], Mred[1]), fmaxf(Mred[2], Mred[3]));
    // ---------------- phase 2: P-fill + P@H + pool ----------------
    for (int tile = 0; tile < 5; ++tile) {
        int r0 = tile * 64;
        for (int q = lane; q < 192; q += 64) {
            int rr = q / 12, c8 = q - rr * 12;
            *(uint4*)&colsW[wv][rr][c8 * 8] =
                *(const uint4*)(cols16 + (size_t)(r0 + wv * 16 + rr) * DEGCAP + c8 * 8);
        }
        int i = r0 + wv * 16 + lr;
        int4 mt = meta[i];
        int sb0 = mt.x, sb1 = mt.y, sb2 = mt.z, sb3 = mt.w;
        float es = esl[i];
        float t0 = es + M;
        float m = fmaxf(t0, LRA * t0);
        f32x4 acc[3];
        #pragma unroll
        for (int t = 0; t < 3; ++t) acc[t] = (f32x4){0.f, 0.f, 0.f, 0.f};
        float dp = 0.f;
        #pragma unroll
        for (int pass = 0; pass < 4; ++pass) {
            for (int q = lane; q < 208; q += 64) {
                int rr = q / 13, cc = q - rr * 13;
                *(uint4*)&AsP[wv][rr][cc * 8] = (uint4){0u, 0u, 0u, 0u};
            }
            int s0 = pass == 0 ? 0 : (pass == 1 ? sb0 : (pass == 2 ? sb1 : sb2));
            int s1 = pass == 0 ? sb0 : (pass == 1 ? sb1 : (pass == 2 ? sb2 : sb3));
            int pofs = pass * 96;
            for (int j = s0 + lq; j < s1; j += 4) {
                int col = colsW[wv][lr][j];
                float t = es + edl[col];
                t = fmaxf(t, LRA * t);
                float w = __expf(t - m);
                dp += w;
                AsP[wv][lr][col - pofs] = __float2bfloat16(w);
            }
            const int nkf = (pass < 3) ? 3 : 1;
            #pragma unroll
            for (int kf = 0; kf < nkf; ++kf) {
                bf16x8 a = *(const bf16x8*)&AsP[wv][lr][kf * 32 + lq * 8];
                #pragma unroll
                for (int t = 0; t < 3; ++t) {
                    bf16x8 bb = *(const bf16x8*)&HT[t * 16 + lr][pofs + kf * 32 + lq * 8];
                    acc[t] = __builtin_amdgcn_mfma_f32_16x16x32_bf16(
                        a, bb, acc[t], 0, 0, 0);
                }
            }
        }
        dp += __shfl_xor(dp, 16, 64);
        dp += __shfl_xor(dp, 32, 64);
        if (lq == 0) denW[wv][lr] = dp;
        float inv[4], part[4];
        #pragma unroll
        for (int j = 0; j < 4; ++j) {
            inv[j] = 1.f / denW[wv][lq * 4 + j];
            part[j] = 0.f;
        }
        #pragma unroll
        for (int t = 0; t < 3; ++t) {
            float pw = pwl[t * 16 + lr];
            #pragma unroll
            for (int j = 0; j < 4; ++j) {
                float v = acc[t][j] * inv[j];
                v = v > 0.f ? v : __expf(v) - 1.f;
                part[j] = fmaf(v, pw, part[j]);
            }
        }
        #pragma unroll
        for (int j = 0; j < 4; ++j) {
            #pragma unroll
            for (int off = 1; off < 16; off <<= 1)
                part[j] += __shfl_xor(part[j], off, 64);
        }
        if (lr == 0) {
            #pragma unroll
            for (int j = 0; j < 4; ++j)
                part2[(size_t)bh * NN + r0 + wv * 16 + lq * 4 + j] = part[j];
        }
    }
}

// ---- K3: x_concat assembly + FC head ---------------------------------------
__global__ __launch_bounds__(256) void k_head(
    const float* __restrict__ xn, const float* __restrict__ part1,
    const float* __restrict__ part2, const float* __restrict__ p1b,
    const float* __restrict__ p2b, const float* __restrict__ e1w,
    const float* __restrict__ e1b, const float* __restrict__ e2w,
    const float* __restrict__ e2b, const float* __restrict__ e3w,
    const float* __restrict__ e3b, const float* __restrict__ cw,
    const float* __restrict__ cb, float* __restrict__ dout) {
    int b = blockIdx.x;
    int tid = threadIdx.x;
    __shared__ float xc[960];
    __shared__ float e1part[2][FC0];
    __shared__ float h1[FC0];
    __shared__ float hh[FC1];
    __shared__ float ft[FC2];
    for (int t = tid; t < NN; t += 256) {
        float x0 = xn[b * NN + t];
        xc[t] = x0;
        dout[b * 960 + t] = x0;
        float s1 = p1b[0];
        #pragma unroll
        for (int h = 0; h < 8; ++h) s1 += part1[(size_t)(b * 8 + h) * NN + t];
        xc[320 + t] = s1;
        dout[b * 960 + 320 + t] = s1;
        float s2 = p2b[0];
        #pragma unroll
        for (int h = 0; h < 4; ++h) s2 += part2[(size_t)(b * 4 + h) * NN + t];
        xc[640 + t] = s2;
        dout[b * 960 + 640 + t] = s2;
    }
    __syncthreads();
    {
        int half = tid >> 7, o = tid & 127;
        if (o < FC0) {
            float a = 0.f;
            int k0 = half * 480;
            for (int k = k0; k < k0 + 480; ++k)
                a = fmaf(xc[k], e1w[k * FC0 + o], a);
            e1part[half][o] = a;
        }
    }
    __syncthreads();
    if (tid < FC0) {
        float a = e1b[tid] + e1part[0][tid] + e1part[1][tid];
        h1[tid] = a > 0.f ? a : expm1f(a);
    }
    __syncthreads();
    if (tid < FC1) {
        float a = e2b[tid];
        for (int k = 0; k < FC0; ++k) a += h1[k] * e2w[k * FC1 + tid];
        hh[tid] = a > 0.f ? a : expm1f(a);
    }
    __syncthreads();
    if (tid < FC2) {
        float a = e3b[tid];
        for (int k = 0; k < FC1; ++k) a += hh[k] * e3w[k * FC2 + tid];
        a = a > 0.f ? a : expm1f(a);
        ft[tid] = a;
        dout[BS * 960 + b * FC2 + tid] = a;
    }
    __syncthreads();
    if (tid < 64) {
        float v = 0.f;
        for (int t = tid; t < FC2; t += 64) v += ft[t] * cw[t];
        #pragma unroll
        for (int off = 32; off > 0; off >>= 1) v += __shfl_xor(v, off, 64);
        if (tid == 0) dout[BS * 960 + BS * FC2 + b] = v + cb[0];
    }
}

extern "C" void kernel_launch(void* const* d_in, const int* in_sizes, int n_in,
                              void* d_out, int out_size, void* d_ws,
                              size_t ws_size, hipStream_t stream) {
    const float* xn  = (const float*)d_in[0];
    const float* adj = (const float*)d_in[1];
    const float* W1  = (const float*)d_in[2];
    const float* a1  = (const float*)d_in[3];
    const float* W2  = (const float*)d_in[4];
    const float* a2  = (const float*)d_in[5];
    const float* p1w = (const float*)d_in[6];
    const float* p1b = (const float*)d_in[7];
    const float* p2w = (const float*)d_in[8];
    const float* p2b = (const float*)d_in[9];
    const float* e1w = (const float*)d_in[10];
    const float* e1b = (const float*)d_in[11];
    const float* e2w = (const float*)d_in[12];
    const float* e2b = (const float*)d_in[13];
    const float* e3w = (const float*)d_in[14];
    const float* e3b = (const float*)d_in[15];
    const float* cw  = (const float*)d_in[16];
    const float* cb  = (const float*)d_in[17];

    char* ws = (char*)d_ws;
    int4*  meta     = (int4*)ws;                               // 5120
    float* c1s      = (float*)(ws + 5120);                     // 32
    float* c1d      = (float*)(ws + 5152);                     // 32 (pad->5248)
    unsigned short* cols16  = (unsigned short*)(ws + 5248);    // 61440 -> 66688
    unsigned short* colsT16 = (unsigned short*)(ws + 66688);   // 61440 -> 128128
    __hip_bfloat16* Bb = (__hip_bfloat16*)(ws + 128128);       // 61440 -> 189568
    __hip_bfloat16* out1b = (__hip_bfloat16*)(ws + 189568);    // 13107200 -> 13296768
    float* part1    = (float*)(ws + 13296768);                 // 1310720 -> 14607488
    float* part2    = (float*)(ws + 14607488);                 // 655360 -> 15262848
    float* dout     = (float*)d_out;

    k_csr<<<NN + 1 + 480, 64, 0, stream>>>(adj, cols16, colsT16, meta,
                                           W1, a1, c1s, c1d, W2, Bb);
    k_l1<<<BS * H1, 320, 0, stream>>>(xn, colsT16, meta, W1, c1s, c1d,
                                      p1w, out1b, part1);
    k_l2<<<BS * H2C, 256, 0, stream>>>(out1b, cols16, meta, Bb, a2, p2w, part2);
    k_head<<<BS, 256, 0, stream>>>(xn, part1, part2, p1b, p2b, e1w, e1b,
                                   e2w, e2b, e3w, e3b, cw, cb, dout);
}